// Round 5
// baseline (542.282 us; speedup 1.0000x reference)
//
#include <hip/hip_runtime.h>
#include <hip/hip_bf16.h>
#include <math.h>

// Problem constants (fixed by setup_inputs)
#define B_  2
#define H_  3072
#define W_  4096
#define HH_ 1536           // H/2 (per-channel height)
#define WW_ 2048           // W/2 (per-channel width)
#define NCH 8              // B*4 channels
#define NROW (NCH*HH_)     // 12288 channel-rows

// ---------- order-preserving float <-> uint key ----------
__device__ __forceinline__ unsigned fkey(float x) {
  unsigned u = __float_as_uint(x);
  return u ^ (unsigned)((((int)u) >> 31) | 0x80000000);
}
__device__ __forceinline__ float funkey(unsigned k) {
  unsigned u = (k & 0x80000000u) ? (k & 0x7FFFFFFFu) : ~k;
  return __uint_as_float(u);
}

// ---------- DPP helpers (compile-time ctrl/rmask) ----------
template<int CTRL, int RMASK>
__device__ __forceinline__ int dppi(int x) {
  return __builtin_amdgcn_update_dpp(0, x, CTRL, RMASK, 0xF, false);
}
template<int CTRL, int RMASK>
__device__ __forceinline__ float dppf(float x) {
  return __int_as_float(
      __builtin_amdgcn_update_dpp(0, __float_as_int(x), CTRL, RMASK, 0xF, false));
}
// Wave64 sum via DPP; total lands in lane 63, readlane -> uniform SGPR.
__device__ __forceinline__ int wave_sum64(int x) {
  x += dppi<0x111, 0xF>(x);   // row_shr:1
  x += dppi<0x112, 0xF>(x);   // row_shr:2
  x += dppi<0x114, 0xF>(x);   // row_shr:4
  x += dppi<0x118, 0xF>(x);   // row_shr:8
  x += dppi<0x142, 0xA>(x);   // row_bcast:15
  x += dppi<0x143, 0xC>(x);   // row_bcast:31
  return __builtin_amdgcn_readlane(x, 63);
}
// sum/sum/max of nonneg floats; valid in lane 63.
__device__ __forceinline__ void wave_red3(float& sa, float& sq, float& mx) {
  sa += dppf<0x111, 0xF>(sa); sq += dppf<0x111, 0xF>(sq); mx = fmaxf(mx, dppf<0x111, 0xF>(mx));
  sa += dppf<0x112, 0xF>(sa); sq += dppf<0x112, 0xF>(sq); mx = fmaxf(mx, dppf<0x112, 0xF>(mx));
  sa += dppf<0x114, 0xF>(sa); sq += dppf<0x114, 0xF>(sq); mx = fmaxf(mx, dppf<0x114, 0xF>(mx));
  sa += dppf<0x118, 0xF>(sa); sq += dppf<0x118, 0xF>(sq); mx = fmaxf(mx, dppf<0x118, 0xF>(mx));
  sa += dppf<0x142, 0xA>(sa); sq += dppf<0x142, 0xA>(sq); mx = fmaxf(mx, dppf<0x142, 0xA>(mx));
  sa += dppf<0x143, 0xC>(sa); sq += dppf<0x143, 0xC>(sq); mx = fmaxf(mx, dppf<0x143, 0xC>(mx));
}

// ---------- in-register 32x32 bit transpose (Hacker's Delight) ----------
__device__ __forceinline__ void transpose32(unsigned (&A)[32]) {
  const unsigned MASKS[5] = {0x0000FFFFu, 0x00FF00FFu, 0x0F0F0F0Fu,
                             0x33333333u, 0x55555555u};
  #pragma unroll
  for (int s = 0; s < 5; ++s) {
    const int j = 16 >> s;
    const unsigned m = MASKS[s];
    #pragma unroll
    for (int k = 0; k < 32; ++k) {
      if ((k & j) == 0) {
        unsigned t = (A[k] ^ (A[k + j] >> j)) & m;
        A[k]     ^= t;
        A[k + j] ^= (t << j);
      }
    }
  }
}

// ---------- exact rank-kk of 64*32 keys (bit-plane radix select) ----------
// Early exit: when the survivor set collapses to a single element, read its
// remaining low bits straight out of that lane's planes (saves ~half the
// rounds on clustered data).
template<int HI>
__device__ __forceinline__ unsigned plane_select(const unsigned (&A)[32],
                                                 int kk, unsigned res) {
  unsigned act = 0xFFFFFFFFu;
  int active = 2048;
  #pragma unroll
  for (int b = HI; b >= 0; --b) {
    const unsigned pl = A[31 - b];
    const unsigned zeros = act & ~pl;
    int c = wave_sum64(__popc(zeros));
    if (kk < c) { act = zeros; active = c; }
    else        { act &= pl; kk -= c; res |= (1u << b); active -= c; }
    if (b > 0 && active == 1) {
      unsigned long long m = __ballot(act != 0u);
      int src = __ffsll(m) - 1;          // owning lane (uniform)
      int j = __ffs((int)act);           // 1-based bit pos; 0 if none
      j = j ? (j - 1) : 0;
      unsigned low = 0u;
      #pragma unroll
      for (int bb = 0; bb < HI; ++bb) {  // compile-time bound; mask runtime b
        if (bb < b) low |= ((A[31 - bb] >> j) & 1u) << bb;
      }
      return res | (unsigned)__builtin_amdgcn_readlane((int)low, src);
    }
  }
  return res;
}

// ---------- kernel 1: row stats + fused channel reduce (last block) ----------
__global__ __launch_bounds__(256) void k_passA(
    const float* __restrict__ raw,
    float* __restrict__ rowmed, float* __restrict__ rowsa,
    float* __restrict__ rowsq,  float* __restrict__ rowmx,
    float* __restrict__ med,    float* __restrict__ feats,
    unsigned* __restrict__ cnt) {
  const int wave = threadIdx.x >> 6, lane = threadIdx.x & 63;
  const int rg  = blockIdx.x * 2 + (wave >> 1);  // raw row
  const int par = wave & 1;                      // column parity
  const int b   = rg / H_;
  const int row = rg - b * H_;
  const int y = row >> 1, cp = row & 1;
  const int c = 2 * cp + par;                    // RGGB channel
  const float4* rowp = (const float4*)(raw + (size_t)rg * W_);

  {
    unsigned A[32];
    float sa = 0.f, sq = 0.f, mx = 0.f;
    #pragma unroll
    for (int i = 0; i < 16; ++i) {
      float4 v = rowp[i * 64 + lane];
      float s0 = par ? v.y : v.x;
      float s1 = par ? v.w : v.z;
      A[2 * i]     = fkey(s0);
      A[2 * i + 1] = fkey(s1);
      float a0 = fabsf(s0), a1 = fabsf(s1);
      sa += a0 + a1;
      sq += s0 * s0 + s1 * s1;
      mx = fmaxf(mx, fmaxf(a0, a1));
    }
    transpose32(A);
    unsigned res = plane_select<31>(A, 1023, 0u);  // lower median of 2048
    wave_red3(sa, sq, mx);
    if (lane == 63) {
      const int cr = (b * 4 + c) * HH_ + y;
      rowmed[cr] = funkey(res);
      rowsa[cr] = sa;  rowsq[cr] = sq;  rowmx[cr] = mx;
    }
  }

  // completion ticket (release: all threads fence, then one atomic)
  __threadfence();
  __syncthreads();
  __shared__ int s_last;
  if (threadIdx.x == 0)
    s_last = (atomicAdd(cnt, 1u) == (unsigned)(gridDim.x - 1)) ? 1 : 0;
  __syncthreads();
  if (!s_last) return;
  __threadfence();                                 // acquire

  // tail: 4 waves x 2 channels each
  for (int q = 0; q < 2; ++q) {
    const int ch = wave * 2 + q;
    unsigned K[32];
    float tsa = 0.f, tsq = 0.f, tmx = 0.f;
    #pragma unroll
    for (int j = 0; j < 24; ++j) {
      int i = ch * HH_ + j * 64 + lane;
      K[j] = fkey(rowmed[i]);
      tsa += rowsa[i];  tsq += rowsq[i];  tmx = fmaxf(tmx, rowmx[i]);
    }
    #pragma unroll
    for (int j = 24; j < 32; ++j) K[j] = 0xFFFFFFFFu;  // +inf pad
    transpose32(K);
    unsigned r = plane_select<31>(K, 767, 0u);     // lower median of 1536
    wave_red3(tsa, tsq, tmx);
    if (lane == 63) {
      med[ch] = funkey(r);
      const float inv = 1.f / (float)(HH_ * WW_);
      const int bb = ch >> 2, cc = ch & 3;
      feats[bb * 16 + cc]      = tsa * inv;   // mean_abs
      feats[bb * 16 + 4 + cc]  = tsq * inv;   // mean_r2
      feats[bb * 16 + 12 + cc] = tmx;         // max_abs
    }
  }
}

// ---------- softplus ----------
__device__ __forceinline__ float spf(float x) {
  return fmaxf(x, 0.f) + log1pf(expf(-fabsf(x)));
}

// ---------- kernel 2: MAD rows + fused chanB + MLP (last block) ----------
__global__ __launch_bounds__(256) void k_passB(
    const float* __restrict__ raw, const float* __restrict__ med,
    float* __restrict__ rowmad, const float* __restrict__ feats,
    const float* __restrict__ W1e, const float* __restrict__ b1e,
    const float* __restrict__ W2e, const float* __restrict__ b2e,
    const float* __restrict__ W1u, const float* __restrict__ b1u,
    const float* __restrict__ W2u, const float* __restrict__ b2u,
    const float* __restrict__ gainp, float* __restrict__ out,
    unsigned* __restrict__ cnt) {
  const int wave = threadIdx.x >> 6, lane = threadIdx.x & 63;
  const int rg  = blockIdx.x * 2 + (wave >> 1);
  const int par = wave & 1;
  const int b   = rg / H_;
  const int row = rg - b * H_;
  const int y = row >> 1, cp = row & 1;
  const int c = 2 * cp + par;
  const float m = med[b * 4 + c];
  const float4* rowp = (const float4*)(raw + (size_t)rg * W_);

  {
    unsigned A[32];
    #pragma unroll
    for (int i = 0; i < 16; ++i) {
      float4 v = rowp[i * 64 + lane];
      float s0 = par ? v.y : v.x;
      float s1 = par ? v.w : v.z;
      A[2 * i]     = fkey(fabsf(s0 - m));
      A[2 * i + 1] = fkey(fabsf(s1 - m));
    }
    transpose32(A);
    // nonneg keys -> bit 31 always set: skip that round.
    unsigned res = plane_select<30>(A, 1023, 0x80000000u);
    if (lane == 0) {
      const int cr = (b * 4 + c) * HH_ + y;
      rowmad[cr] = funkey(res);
    }
  }

  __threadfence();
  __syncthreads();
  __shared__ int s_last;
  if (threadIdx.x == 0)
    s_last = (atomicAdd(cnt, 1u) == (unsigned)(gridDim.x - 1)) ? 1 : 0;
  __syncthreads();
  if (!s_last) return;
  __threadfence();                                 // acquire

  // ---- fused chanB + MLP in the last block ----
  __shared__ float xs[2][16];
  __shared__ float he[2][128];
  __shared__ float hu[2][128];
  const int t = threadIdx.x;
  if (t < 32) ((float*)xs)[t] = feats[t];          // mean/var/max from pass A
  __syncthreads();

  for (int q = 0; q < 2; ++q) {                    // 4 waves x 2 channels
    const int ch = wave * 2 + q;
    unsigned K[32];
    #pragma unroll
    for (int j = 0; j < 24; ++j)
      K[j] = fkey(rowmad[ch * HH_ + j * 64 + lane]);
    #pragma unroll
    for (int j = 24; j < 32; ++j) K[j] = 0xFFFFFFFFu;
    transpose32(K);
    unsigned r = plane_select<30>(K, 767, 0x80000000u);
    if (lane == 63) {
      float mad = funkey(r);
      float sg = 1.4826f * mad;
      ((float*)xs)[(ch >> 2) * 16 + 8 + (ch & 3)] = sg * sg + 1e-8f;  // mad_vars
    }
  }
  __syncthreads();

  {  // layer 1: 2 batches x 128 hidden
    const int bb = t >> 7, j = t & 127;
    const float4* w1e = (const float4*)(W1e + j * 16);
    const float4* w1u = (const float4*)(W1u + j * 16);
    float se = b1e[j], su = b1u[j];
    #pragma unroll
    for (int q = 0; q < 4; ++q) {
      float4 we = w1e[q], wu = w1u[q];
      float x0 = xs[bb][4 * q], x1 = xs[bb][4 * q + 1];
      float x2 = xs[bb][4 * q + 2], x3 = xs[bb][4 * q + 3];
      se += x0 * spf(we.x) + x1 * spf(we.y) + x2 * spf(we.z) + x3 * spf(we.w);
      su += x0 * spf(wu.x) + x1 * spf(wu.y) + x2 * spf(wu.z) + x3 * spf(wu.w);
    }
    he[bb][j] = spf(se);
    hu[bb][j] = spf(su);
  }
  __syncthreads();
  {  // emb head: 128 outputs x 2 threads
    const int pair = t >> 1, half = t & 1;
    const int bb = pair >> 6, d = pair & 63;
    const float4* w2 = (const float4*)(W2e + d * 128 + half * 64);
    float s = 0.f;
    #pragma unroll
    for (int q = 0; q < 16; ++q) {
      float4 w = w2[q];
      const int j = half * 64 + 4 * q;
      s += he[bb][j]     * spf(w.x) + he[bb][j + 1] * spf(w.y)
         + he[bb][j + 2] * spf(w.z) + he[bb][j + 3] * spf(w.w);
    }
    s += __shfl_xor(s, 1);
    if (half == 0) out[bb * 64 + d] = gainp[0] * (s + b2e[d]);
  }
  if (t >= 192) {  // u head on wave 3
    const int tt = t - 192, bb = tt >> 5, l = tt & 31;
    float4 w = ((const float4*)W2u)[l];
    float s = hu[bb][4 * l]     * spf(w.x) + hu[bb][4 * l + 1] * spf(w.y)
            + hu[bb][4 * l + 2] * spf(w.z) + hu[bb][4 * l + 3] * spf(w.w);
    #pragma unroll
    for (int off = 1; off < 32; off <<= 1) s += __shfl_xor(s, off);
    if (l == 0) out[128 + bb] = s + b2u[0];
  }
}

extern "C" void kernel_launch(void* const* d_in, const int* in_sizes, int n_in,
                              void* d_out, int out_size, void* d_ws, size_t ws_size,
                              hipStream_t stream) {
  const float* raw  = (const float*)d_in[0];
  const float* W1e  = (const float*)d_in[1];
  const float* b1e  = (const float*)d_in[2];
  const float* W2e  = (const float*)d_in[3];
  const float* b2e  = (const float*)d_in[4];
  const float* W1u  = (const float*)d_in[5];
  const float* b1u  = (const float*)d_in[6];
  const float* W2u  = (const float*)d_in[7];
  const float* b2u  = (const float*)d_in[8];
  const float* gain = (const float*)d_in[9];
  float* out = (float*)d_out;

  float* ws     = (float*)d_ws;
  float* rowmed = ws;                   // 12288
  float* rowsa  = ws + NROW;            // 12288
  float* rowsq  = ws + 2 * NROW;        // 12288
  float* rowmx  = ws + 3 * NROW;        // 12288
  float* med    = ws + 4 * NROW;        // 8
  float* rowmad = ws + 4 * NROW + 8;    // 12288
  float* feats  = ws + 5 * NROW + 8;    // 32
  unsigned* cnt = (unsigned*)(ws + 5 * NROW + 8 + 32);  // 2 counters

  // counters must be zero every call (ws is poisoned / left dirty otherwise)
  hipMemsetAsync(cnt, 0, 2 * sizeof(unsigned), stream);

  const int blocks = (B_ * H_) / 2;     // 3072 blocks, 4 waves each

  k_passA<<<blocks, 256, 0, stream>>>(raw, rowmed, rowsa, rowsq, rowmx,
                                      med, feats, cnt);
  k_passB<<<blocks, 256, 0, stream>>>(raw, med, rowmad, feats,
                                      W1e, b1e, W2e, b2e,
                                      W1u, b1u, W2u, b2u,
                                      gain, out, cnt + 1);
}

// Round 6
// 163.819 us; speedup vs baseline: 3.3102x; 3.3102x over previous
//
#include <hip/hip_runtime.h>
#include <hip/hip_bf16.h>
#include <math.h>

// Problem constants (fixed by setup_inputs)
#define B_  2
#define H_  3072
#define W_  4096
#define HH_ 1536           // H/2 (per-channel height)
#define WW_ 2048           // W/2 (per-channel width)
#define NCH 8              // B*4 channels
#define NROW (NCH*HH_)     // 12288 channel-rows

// ---------- order-preserving float <-> uint key ----------
__device__ __forceinline__ unsigned fkey(float x) {
  unsigned u = __float_as_uint(x);
  return u ^ (unsigned)((((int)u) >> 31) | 0x80000000);
}
__device__ __forceinline__ float funkey(unsigned k) {
  unsigned u = (k & 0x80000000u) ? (k & 0x7FFFFFFFu) : ~k;
  return __uint_as_float(u);
}

// ---------- DPP helpers (compile-time ctrl/rmask) ----------
template<int CTRL, int RMASK>
__device__ __forceinline__ int dppi(int x) {
  return __builtin_amdgcn_update_dpp(0, x, CTRL, RMASK, 0xF, false);
}
template<int CTRL, int RMASK>
__device__ __forceinline__ float dppf(float x) {
  return __int_as_float(
      __builtin_amdgcn_update_dpp(0, __float_as_int(x), CTRL, RMASK, 0xF, false));
}

// Wave64 sum via DPP; total in lane 63 -> readlane (uniform SGPR).
__device__ __forceinline__ int wave_sum64(int x) {
  x += dppi<0x111, 0xF>(x);   // row_shr:1
  x += dppi<0x112, 0xF>(x);   // row_shr:2
  x += dppi<0x114, 0xF>(x);   // row_shr:4
  x += dppi<0x118, 0xF>(x);   // row_shr:8
  x += dppi<0x142, 0xA>(x);   // row_bcast:15
  x += dppi<0x143, 0xC>(x);   // row_bcast:31
  return __builtin_amdgcn_readlane(x, 63);
}
// Three independent wave sums, interleaved for ILP (one chain's latency).
__device__ __forceinline__ void wave_sum64_x3(int& x, int& y, int& z) {
  x += dppi<0x111, 0xF>(x); y += dppi<0x111, 0xF>(y); z += dppi<0x111, 0xF>(z);
  x += dppi<0x112, 0xF>(x); y += dppi<0x112, 0xF>(y); z += dppi<0x112, 0xF>(z);
  x += dppi<0x114, 0xF>(x); y += dppi<0x114, 0xF>(y); z += dppi<0x114, 0xF>(z);
  x += dppi<0x118, 0xF>(x); y += dppi<0x118, 0xF>(y); z += dppi<0x118, 0xF>(z);
  x += dppi<0x142, 0xA>(x); y += dppi<0x142, 0xA>(y); z += dppi<0x142, 0xA>(z);
  x += dppi<0x143, 0xC>(x); y += dppi<0x143, 0xC>(y); z += dppi<0x143, 0xC>(z);
  x = __builtin_amdgcn_readlane(x, 63);
  y = __builtin_amdgcn_readlane(y, 63);
  z = __builtin_amdgcn_readlane(z, 63);
}
// sum/sum/max of nonneg floats; valid in lane 63.
__device__ __forceinline__ void wave_red3(float& sa, float& sq, float& mx) {
  sa += dppf<0x111, 0xF>(sa); sq += dppf<0x111, 0xF>(sq); mx = fmaxf(mx, dppf<0x111, 0xF>(mx));
  sa += dppf<0x112, 0xF>(sa); sq += dppf<0x112, 0xF>(sq); mx = fmaxf(mx, dppf<0x112, 0xF>(mx));
  sa += dppf<0x114, 0xF>(sa); sq += dppf<0x114, 0xF>(sq); mx = fmaxf(mx, dppf<0x114, 0xF>(mx));
  sa += dppf<0x118, 0xF>(sa); sq += dppf<0x118, 0xF>(sq); mx = fmaxf(mx, dppf<0x118, 0xF>(mx));
  sa += dppf<0x142, 0xA>(sa); sq += dppf<0x142, 0xA>(sq); mx = fmaxf(mx, dppf<0x142, 0xA>(mx));
  sa += dppf<0x143, 0xC>(sa); sq += dppf<0x143, 0xC>(sq); mx = fmaxf(mx, dppf<0x143, 0xC>(mx));
}

// ---------- in-register 32x32 bit transpose (Hacker's Delight) ----------
__device__ __forceinline__ void transpose32(unsigned (&A)[32]) {
  const unsigned MASKS[5] = {0x0000FFFFu, 0x00FF00FFu, 0x0F0F0F0Fu,
                             0x33333333u, 0x55555555u};
  #pragma unroll
  for (int s = 0; s < 5; ++s) {
    const int j = 16 >> s;
    const unsigned m = MASKS[s];
    #pragma unroll
    for (int k = 0; k < 32; ++k) {
      if ((k & j) == 0) {
        unsigned t = (A[k] ^ (A[k + j] >> j)) & m;
        A[k]     ^= t;
        A[k + j] ^= (t << j);
      }
    }
  }
}

// ---------- exact rank-kk of 64*32 keys: 2-bit radix on bit-planes ----------
// Resolves bits HI..0 (HI odd -> (HI+1)/2 pair rounds; HI even -> one single
// round then pairs). kk, res, counts stay uniform (scalar branches).
template<int HI>
__device__ __forceinline__ unsigned plane_select(const unsigned (&A)[32],
                                                 int kk, unsigned res) {
  unsigned act = 0xFFFFFFFFu;
  if ((HI & 1) == 0) {                      // lone top bit
    const unsigned pl = A[31 - HI];
    unsigned zeros = act & ~pl;
    int c = wave_sum64(__popc(zeros));
    if (kk < c) act = zeros;
    else { act &= pl; kk -= c; res |= (1u << HI); }
  }
  constexpr int TOP = (HI & 1) ? HI : HI - 1;
  #pragma unroll
  for (int b = TOP; b >= 1; b -= 2) {       // bits (b, b-1)
    const unsigned p1 = A[31 - b], p0 = A[31 - (b - 1)];
    const unsigned n1 = act & ~p1, y1 = act & p1;
    const unsigned a00 = n1 & ~p0, a01 = n1 & p0, a10 = y1 & ~p0;
    int c00 = __popc(a00), c01 = __popc(a01), c10 = __popc(a10);
    wave_sum64_x3(c00, c01, c10);
    if (kk < c00)            { act = a00; }
    else if (kk < c00 + c01) { act = a01; kk -= c00;        res |= 1u << (b - 1); }
    else if (kk < c00 + c01 + c10)
                             { act = a10; kk -= c00 + c01;  res |= 1u << b; }
    else { act = y1 & p0; kk -= c00 + c01 + c10; res |= (3u << (b - 1)); }
  }
  return res;
}

// ---------- pass A: one wave per channel-row ----------
__global__ __launch_bounds__(256, 8) void k_rowstats(
    const float* __restrict__ raw,
    float* __restrict__ rowmed, float* __restrict__ rowsa,
    float* __restrict__ rowsq,  float* __restrict__ rowmx) {
  const int wave = threadIdx.x >> 6, lane = threadIdx.x & 63;
  const int rg  = blockIdx.x * 2 + (wave >> 1);  // raw row 0..B*H-1
  const int par = wave & 1;                      // column parity
  const int b   = rg / H_;
  const int row = rg - b * H_;
  const int y = row >> 1, cp = row & 1;
  const int c = 2 * cp + par;                    // RGGB channel
  const float4* rowp = (const float4*)(raw + (size_t)rg * W_);

  unsigned A[32];
  float sa = 0.f, sq = 0.f, mx = 0.f;
  #pragma unroll
  for (int i = 0; i < 16; ++i) {
    float4 v = rowp[i * 64 + lane];              // coalesced 16B/lane
    float s0 = par ? v.y : v.x;
    float s1 = par ? v.w : v.z;
    A[2 * i]     = fkey(s0);
    A[2 * i + 1] = fkey(s1);
    float a0 = fabsf(s0), a1 = fabsf(s1);
    sa += a0 + a1;
    sq += s0 * s0 + s1 * s1;
    mx = fmaxf(mx, fmaxf(a0, a1));
  }
  transpose32(A);
  unsigned res = plane_select<31>(A, 1023, 0u);  // lower median of 2048
  wave_red3(sa, sq, mx);
  if (lane == 63) {
    const int cr = (b * 4 + c) * HH_ + y;
    rowmed[cr] = funkey(res);
    rowsa[cr] = sa;  rowsq[cr] = sq;  rowmx[cr] = mx;
  }
}

// ---------- reduce A: 1 block, 8 waves, one channel each ----------
__global__ __launch_bounds__(512) void k_chanA(
    const float* __restrict__ rowmed, const float* __restrict__ rowsa,
    const float* __restrict__ rowsq,  const float* __restrict__ rowmx,
    float* __restrict__ med, float* __restrict__ feats) {
  const int ch = threadIdx.x >> 6, lane = threadIdx.x & 63;
  unsigned A[32];
  float sa = 0.f, sq = 0.f, mx = 0.f;
  #pragma unroll
  for (int j = 0; j < 24; ++j) {
    int i = ch * HH_ + j * 64 + lane;
    A[j] = fkey(rowmed[i]);
    sa += rowsa[i];  sq += rowsq[i];  mx = fmaxf(mx, rowmx[i]);
  }
  #pragma unroll
  for (int j = 24; j < 32; ++j) A[j] = 0xFFFFFFFFu;  // +inf pad (rank 767 < 1536)
  transpose32(A);
  unsigned res = plane_select<31>(A, 767, 0u);       // lower median of 1536
  wave_red3(sa, sq, mx);
  if (lane == 63) {
    med[ch] = funkey(res);
    const float inv = 1.f / (float)(HH_ * WW_);
    const int b = ch >> 2, c = ch & 3;
    feats[b * 16 + c]      = sa * inv;   // mean_abs
    feats[b * 16 + 4 + c]  = sq * inv;   // mean_r2
    feats[b * 16 + 12 + c] = mx;         // max_abs
  }
}

// ---------- pass B: per-row median of |x - med(channel)| ----------
__global__ __launch_bounds__(256, 8) void k_madrows(
    const float* __restrict__ raw, const float* __restrict__ med,
    float* __restrict__ rowmad) {
  const int wave = threadIdx.x >> 6, lane = threadIdx.x & 63;
  const int rg  = blockIdx.x * 2 + (wave >> 1);
  const int par = wave & 1;
  const int b   = rg / H_;
  const int row = rg - b * H_;
  const int y = row >> 1, cp = row & 1;
  const int c = 2 * cp + par;
  const float m = med[b * 4 + c];
  const float4* rowp = (const float4*)(raw + (size_t)rg * W_);

  unsigned A[32];
  #pragma unroll
  for (int i = 0; i < 16; ++i) {
    float4 v = rowp[i * 64 + lane];
    float s0 = par ? v.y : v.x;
    float s1 = par ? v.w : v.z;
    A[2 * i]     = fkey(fabsf(s0 - m));
    A[2 * i + 1] = fkey(fabsf(s1 - m));
  }
  transpose32(A);
  // keys all nonneg -> bit 31 always set: resolve bits 30..0.
  unsigned res = plane_select<30>(A, 1023, 0x80000000u);
  if (lane == 0) {
    const int cr = (b * 4 + c) * HH_ + y;
    rowmad[cr] = funkey(res);
  }
}

// ---------- softplus ----------
__device__ __forceinline__ float spf(float x) {
  return fmaxf(x, 0.f) + log1pf(expf(-fabsf(x)));
}

// ---------- tail: chanB medians + both MLPs in one block ----------
__global__ __launch_bounds__(256) void k_tail(
    const float* __restrict__ rowmad, const float* __restrict__ feats,
    const float* __restrict__ W1e, const float* __restrict__ b1e,
    const float* __restrict__ W2e, const float* __restrict__ b2e,
    const float* __restrict__ W1u, const float* __restrict__ b1u,
    const float* __restrict__ W2u, const float* __restrict__ b2u,
    const float* __restrict__ gainp, float* __restrict__ out) {
  const int wave = threadIdx.x >> 6, lane = threadIdx.x & 63;
  const int t = threadIdx.x;
  __shared__ float xs[2][16];
  __shared__ float he[2][128];
  __shared__ float hu[2][128];
  if (t < 32) ((float*)xs)[t] = feats[t];      // mean/var/max from pass A
  __syncthreads();

  for (int q = 0; q < 2; ++q) {                // 4 waves x 2 channels
    const int ch = wave * 2 + q;
    unsigned K[32];
    #pragma unroll
    for (int j = 0; j < 24; ++j)
      K[j] = fkey(rowmad[ch * HH_ + j * 64 + lane]);
    #pragma unroll
    for (int j = 24; j < 32; ++j) K[j] = 0xFFFFFFFFu;
    transpose32(K);
    unsigned r = plane_select<30>(K, 767, 0x80000000u);  // nonneg keys
    if (lane == 63) {
      float mad = funkey(r);
      float sg = 1.4826f * mad;
      ((float*)xs)[(ch >> 2) * 16 + 8 + (ch & 3)] = sg * sg + 1e-8f;  // mad_vars
    }
  }
  __syncthreads();

  {  // layer 1: 2 batches x 128 hidden
    const int bb = t >> 7, j = t & 127;
    const float4* w1e = (const float4*)(W1e + j * 16);
    const float4* w1u = (const float4*)(W1u + j * 16);
    float se = b1e[j], su = b1u[j];
    #pragma unroll
    for (int q = 0; q < 4; ++q) {
      float4 we = w1e[q], wu = w1u[q];
      float x0 = xs[bb][4 * q], x1 = xs[bb][4 * q + 1];
      float x2 = xs[bb][4 * q + 2], x3 = xs[bb][4 * q + 3];
      se += x0 * spf(we.x) + x1 * spf(we.y) + x2 * spf(we.z) + x3 * spf(we.w);
      su += x0 * spf(wu.x) + x1 * spf(wu.y) + x2 * spf(wu.z) + x3 * spf(wu.w);
    }
    he[bb][j] = spf(se);
    hu[bb][j] = spf(su);
  }
  __syncthreads();
  {  // emb head: 128 outputs x 2 threads (64 terms each)
    const int pair = t >> 1, half = t & 1;
    const int bb = pair >> 6, d = pair & 63;
    const float4* w2 = (const float4*)(W2e + d * 128 + half * 64);
    float s = 0.f;
    #pragma unroll
    for (int q = 0; q < 16; ++q) {
      float4 w = w2[q];
      const int j = half * 64 + 4 * q;
      s += he[bb][j]     * spf(w.x) + he[bb][j + 1] * spf(w.y)
         + he[bb][j + 2] * spf(w.z) + he[bb][j + 3] * spf(w.w);
    }
    s += __shfl_xor(s, 1);
    if (half == 0) out[bb * 64 + d] = gainp[0] * (s + b2e[d]);
  }
  if (t >= 192) {  // u head on wave 3
    const int tt = t - 192, bb = tt >> 5, l = tt & 31;
    float4 w = ((const float4*)W2u)[l];
    float s = hu[bb][4 * l]     * spf(w.x) + hu[bb][4 * l + 1] * spf(w.y)
            + hu[bb][4 * l + 2] * spf(w.z) + hu[bb][4 * l + 3] * spf(w.w);
    #pragma unroll
    for (int off = 1; off < 32; off <<= 1) s += __shfl_xor(s, off);
    if (l == 0) out[128 + bb] = s + b2u[0];
  }
}

extern "C" void kernel_launch(void* const* d_in, const int* in_sizes, int n_in,
                              void* d_out, int out_size, void* d_ws, size_t ws_size,
                              hipStream_t stream) {
  const float* raw  = (const float*)d_in[0];
  const float* W1e  = (const float*)d_in[1];
  const float* b1e  = (const float*)d_in[2];
  const float* W2e  = (const float*)d_in[3];
  const float* b2e  = (const float*)d_in[4];
  const float* W1u  = (const float*)d_in[5];
  const float* b1u  = (const float*)d_in[6];
  const float* W2u  = (const float*)d_in[7];
  const float* b2u  = (const float*)d_in[8];
  const float* gain = (const float*)d_in[9];
  float* out = (float*)d_out;

  float* ws     = (float*)d_ws;
  float* rowmed = ws;                   // 12288
  float* rowsa  = ws + NROW;            // 12288
  float* rowsq  = ws + 2 * NROW;        // 12288
  float* rowmx  = ws + 3 * NROW;        // 12288
  float* med    = ws + 4 * NROW;        // 8
  float* rowmad = ws + 4 * NROW + 8;    // 12288
  float* feats  = ws + 5 * NROW + 8;    // 32

  const int blocks = (B_ * H_) / 2;     // 3072 blocks, 4 waves each

  k_rowstats<<<blocks, 256, 0, stream>>>(raw, rowmed, rowsa, rowsq, rowmx);
  k_chanA<<<1, 512, 0, stream>>>(rowmed, rowsa, rowsq, rowmx, med, feats);
  k_madrows<<<blocks, 256, 0, stream>>>(raw, med, rowmad);
  k_tail<<<1, 256, 0, stream>>>(rowmad, feats,
                                W1e, b1e, W2e, b2e,
                                W1u, b1u, W2u, b2u, gain, out);
}

// Round 7
// 96.074 us; speedup vs baseline: 5.6444x; 1.7051x over previous
//
#include <hip/hip_runtime.h>
#include <hip/hip_bf16.h>
#include <math.h>

// Problem constants (fixed by setup_inputs)
#define B_  2
#define H_  3072
#define W_  4096
#define HH_ 1536           // H/2 (per-channel height)
#define WW_ 2048           // W/2 (per-channel width)
#define NCH 8              // B*4 channels
#define NROW (NCH*HH_)     // 12288 channel-rows

// ---------- order-preserving float <-> uint key ----------
__device__ __forceinline__ unsigned fkey(float x) {
  unsigned u = __float_as_uint(x);
  return u ^ (unsigned)((((int)u) >> 31) | 0x80000000);
}
__device__ __forceinline__ float funkey(unsigned k) {
  unsigned u = (k & 0x80000000u) ? (k & 0x7FFFFFFFu) : ~k;
  return __uint_as_float(u);
}

// ---------- DPP helpers (compile-time ctrl/rmask) ----------
template<int CTRL, int RMASK>
__device__ __forceinline__ int dppi(int x) {
  return __builtin_amdgcn_update_dpp(0, x, CTRL, RMASK, 0xF, false);
}
template<int CTRL, int RMASK>
__device__ __forceinline__ float dppf(float x) {
  return __int_as_float(
      __builtin_amdgcn_update_dpp(0, __float_as_int(x), CTRL, RMASK, 0xF, false));
}

// Wave64 sum via DPP; total in lane 63 -> readlane (uniform SGPR).
__device__ __forceinline__ int wave_sum64(int x) {
  x += dppi<0x111, 0xF>(x);   // row_shr:1
  x += dppi<0x112, 0xF>(x);   // row_shr:2
  x += dppi<0x114, 0xF>(x);   // row_shr:4
  x += dppi<0x118, 0xF>(x);   // row_shr:8
  x += dppi<0x142, 0xA>(x);   // row_bcast:15
  x += dppi<0x143, 0xC>(x);   // row_bcast:31
  return __builtin_amdgcn_readlane(x, 63);
}
// Three independent wave sums, interleaved for ILP (one chain's latency).
__device__ __forceinline__ void wave_sum64_x3(int& x, int& y, int& z) {
  x += dppi<0x111, 0xF>(x); y += dppi<0x111, 0xF>(y); z += dppi<0x111, 0xF>(z);
  x += dppi<0x112, 0xF>(x); y += dppi<0x112, 0xF>(y); z += dppi<0x112, 0xF>(z);
  x += dppi<0x114, 0xF>(x); y += dppi<0x114, 0xF>(y); z += dppi<0x114, 0xF>(z);
  x += dppi<0x118, 0xF>(x); y += dppi<0x118, 0xF>(y); z += dppi<0x118, 0xF>(z);
  x += dppi<0x142, 0xA>(x); y += dppi<0x142, 0xA>(y); z += dppi<0x142, 0xA>(z);
  x += dppi<0x143, 0xC>(x); y += dppi<0x143, 0xC>(y); z += dppi<0x143, 0xC>(z);
  x = __builtin_amdgcn_readlane(x, 63);
  y = __builtin_amdgcn_readlane(y, 63);
  z = __builtin_amdgcn_readlane(z, 63);
}
// sum/sum/max of nonneg floats; valid in lane 63.
__device__ __forceinline__ void wave_red3(float& sa, float& sq, float& mx) {
  sa += dppf<0x111, 0xF>(sa); sq += dppf<0x111, 0xF>(sq); mx = fmaxf(mx, dppf<0x111, 0xF>(mx));
  sa += dppf<0x112, 0xF>(sa); sq += dppf<0x112, 0xF>(sq); mx = fmaxf(mx, dppf<0x112, 0xF>(mx));
  sa += dppf<0x114, 0xF>(sa); sq += dppf<0x114, 0xF>(sq); mx = fmaxf(mx, dppf<0x114, 0xF>(mx));
  sa += dppf<0x118, 0xF>(sa); sq += dppf<0x118, 0xF>(sq); mx = fmaxf(mx, dppf<0x118, 0xF>(mx));
  sa += dppf<0x142, 0xA>(sa); sq += dppf<0x142, 0xA>(sq); mx = fmaxf(mx, dppf<0x142, 0xA>(mx));
  sa += dppf<0x143, 0xC>(sa); sq += dppf<0x143, 0xC>(sq); mx = fmaxf(mx, dppf<0x143, 0xC>(mx));
}

// ---------- in-register 32x32 bit transpose (Hacker's Delight) ----------
__device__ __forceinline__ void transpose32(unsigned (&A)[32]) {
  const unsigned MASKS[5] = {0x0000FFFFu, 0x00FF00FFu, 0x0F0F0F0Fu,
                             0x33333333u, 0x55555555u};
  #pragma unroll
  for (int s = 0; s < 5; ++s) {
    const int j = 16 >> s;
    const unsigned m = MASKS[s];
    #pragma unroll
    for (int k = 0; k < 32; ++k) {
      if ((k & j) == 0) {
        unsigned t = (A[k] ^ (A[k + j] >> j)) & m;
        A[k]     ^= t;
        A[k + j] ^= (t << j);
      }
    }
  }
}

// ---------- exact rank-kk of 64*32 keys: 2-bit radix on bit-planes ----------
// Resolves bits HI..0. kk, res, counts stay uniform (scalar branches).
// Verified exact on-device (absmax 0 in round 6).
template<int HI>
__device__ __forceinline__ unsigned plane_select(const unsigned (&A)[32],
                                                 int kk, unsigned res) {
  unsigned act = 0xFFFFFFFFu;
  if ((HI & 1) == 0) {                      // lone top bit
    const unsigned pl = A[31 - HI];
    unsigned zeros = act & ~pl;
    int c = wave_sum64(__popc(zeros));
    if (kk < c) act = zeros;
    else { act &= pl; kk -= c; res |= (1u << HI); }
  }
  constexpr int TOP = (HI & 1) ? HI : HI - 1;
  #pragma unroll
  for (int b = TOP; b >= 1; b -= 2) {       // bits (b, b-1)
    const unsigned p1 = A[31 - b], p0 = A[31 - (b - 1)];
    const unsigned n1 = act & ~p1, y1 = act & p1;
    const unsigned a00 = n1 & ~p0, a01 = n1 & p0, a10 = y1 & ~p0;
    int c00 = __popc(a00), c01 = __popc(a01), c10 = __popc(a10);
    wave_sum64_x3(c00, c01, c10);
    if (kk < c00)            { act = a00; }
    else if (kk < c00 + c01) { act = a01; kk -= c00;        res |= 1u << (b - 1); }
    else if (kk < c00 + c01 + c10)
                             { act = a10; kk -= c00 + c01;  res |= 1u << b; }
    else { act = y1 & p0; kk -= c00 + c01 + c10; res |= (3u << (b - 1)); }
  }
  return res;
}

// ---------- pass A: one wave per channel-row ----------
// NOTE: no min-waves clause — forcing 8 waves/EU spilled A[32] to scratch
// (round 6: VGPR=32, WRITE_SIZE 220MB, 114us). Natural ~84 VGPR, 4 waves/EU.
__global__ __launch_bounds__(256) void k_rowstats(
    const float* __restrict__ raw,
    float* __restrict__ rowmed, float* __restrict__ rowsa,
    float* __restrict__ rowsq,  float* __restrict__ rowmx) {
  const int wave = threadIdx.x >> 6, lane = threadIdx.x & 63;
  const int rg  = blockIdx.x * 2 + (wave >> 1);  // raw row 0..B*H-1
  const int par = wave & 1;                      // column parity
  const int b   = rg / H_;
  const int row = rg - b * H_;
  const int y = row >> 1, cp = row & 1;
  const int c = 2 * cp + par;                    // RGGB channel
  const float4* rowp = (const float4*)(raw + (size_t)rg * W_);

  unsigned A[32];
  float sa = 0.f, sq = 0.f, mx = 0.f;
  #pragma unroll
  for (int i = 0; i < 16; ++i) {
    float4 v = rowp[i * 64 + lane];              // coalesced 16B/lane
    float s0 = par ? v.y : v.x;
    float s1 = par ? v.w : v.z;
    A[2 * i]     = fkey(s0);
    A[2 * i + 1] = fkey(s1);
    float a0 = fabsf(s0), a1 = fabsf(s1);
    sa += a0 + a1;
    sq += s0 * s0 + s1 * s1;
    mx = fmaxf(mx, fmaxf(a0, a1));
  }
  wave_red3(sa, sq, mx);                         // stats regs die early
  transpose32(A);
  unsigned res = plane_select<31>(A, 1023, 0u);  // lower median of 2048
  if (lane == 63) {
    const int cr = (b * 4 + c) * HH_ + y;
    rowmed[cr] = funkey(res);
    rowsa[cr] = sa;  rowsq[cr] = sq;  rowmx[cr] = mx;
  }
}

// ---------- reduce A: 1 block, 8 waves, one channel each ----------
__global__ __launch_bounds__(512) void k_chanA(
    const float* __restrict__ rowmed, const float* __restrict__ rowsa,
    const float* __restrict__ rowsq,  const float* __restrict__ rowmx,
    float* __restrict__ med, float* __restrict__ feats) {
  const int ch = threadIdx.x >> 6, lane = threadIdx.x & 63;
  unsigned A[32];
  float sa = 0.f, sq = 0.f, mx = 0.f;
  #pragma unroll
  for (int j = 0; j < 24; ++j) {
    int i = ch * HH_ + j * 64 + lane;
    A[j] = fkey(rowmed[i]);
    sa += rowsa[i];  sq += rowsq[i];  mx = fmaxf(mx, rowmx[i]);
  }
  #pragma unroll
  for (int j = 24; j < 32; ++j) A[j] = 0xFFFFFFFFu;  // +inf pad (rank 767 < 1536)
  wave_red3(sa, sq, mx);
  transpose32(A);
  unsigned res = plane_select<31>(A, 767, 0u);       // lower median of 1536
  if (lane == 63) {
    med[ch] = funkey(res);
    const float inv = 1.f / (float)(HH_ * WW_);
    const int b = ch >> 2, c = ch & 3;
    feats[b * 16 + c]      = sa * inv;   // mean_abs
    feats[b * 16 + 4 + c]  = sq * inv;   // mean_r2
    feats[b * 16 + 12 + c] = mx;         // max_abs
  }
}

// ---------- pass B: per-row median of |x - med(channel)| ----------
__global__ __launch_bounds__(256) void k_madrows(
    const float* __restrict__ raw, const float* __restrict__ med,
    float* __restrict__ rowmad) {
  const int wave = threadIdx.x >> 6, lane = threadIdx.x & 63;
  const int rg  = blockIdx.x * 2 + (wave >> 1);
  const int par = wave & 1;
  const int b   = rg / H_;
  const int row = rg - b * H_;
  const int y = row >> 1, cp = row & 1;
  const int c = 2 * cp + par;
  const float m = med[b * 4 + c];
  const float4* rowp = (const float4*)(raw + (size_t)rg * W_);

  unsigned A[32];
  #pragma unroll
  for (int i = 0; i < 16; ++i) {
    float4 v = rowp[i * 64 + lane];
    float s0 = par ? v.y : v.x;
    float s1 = par ? v.w : v.z;
    A[2 * i]     = fkey(fabsf(s0 - m));
    A[2 * i + 1] = fkey(fabsf(s1 - m));
  }
  transpose32(A);
  // keys all nonneg -> bit 31 always set: resolve bits 30..0.
  unsigned res = plane_select<30>(A, 1023, 0x80000000u);
  if (lane == 0) {
    const int cr = (b * 4 + c) * HH_ + y;
    rowmad[cr] = funkey(res);
  }
}

// ---------- softplus ----------
__device__ __forceinline__ float spf(float x) {
  return fmaxf(x, 0.f) + log1pf(expf(-fabsf(x)));
}

// ---------- tail: chanB medians + both MLPs in one block ----------
__global__ __launch_bounds__(256) void k_tail(
    const float* __restrict__ rowmad, const float* __restrict__ feats,
    const float* __restrict__ W1e, const float* __restrict__ b1e,
    const float* __restrict__ W2e, const float* __restrict__ b2e,
    const float* __restrict__ W1u, const float* __restrict__ b1u,
    const float* __restrict__ W2u, const float* __restrict__ b2u,
    const float* __restrict__ gainp, float* __restrict__ out) {
  const int wave = threadIdx.x >> 6, lane = threadIdx.x & 63;
  const int t = threadIdx.x;
  __shared__ float xs[2][16];
  __shared__ float he[2][128];
  __shared__ float hu[2][128];
  if (t < 32) ((float*)xs)[t] = feats[t];      // mean/var/max from pass A
  __syncthreads();

  for (int q = 0; q < 2; ++q) {                // 4 waves x 2 channels
    const int ch = wave * 2 + q;
    unsigned K[32];
    #pragma unroll
    for (int j = 0; j < 24; ++j)
      K[j] = fkey(rowmad[ch * HH_ + j * 64 + lane]);
    #pragma unroll
    for (int j = 24; j < 32; ++j) K[j] = 0xFFFFFFFFu;
    transpose32(K);
    unsigned r = plane_select<30>(K, 767, 0x80000000u);  // nonneg keys
    if (lane == 63) {
      float mad = funkey(r);
      float sg = 1.4826f * mad;
      ((float*)xs)[(ch >> 2) * 16 + 8 + (ch & 3)] = sg * sg + 1e-8f;  // mad_vars
    }
  }
  __syncthreads();

  {  // layer 1: 2 batches x 128 hidden
    const int bb = t >> 7, j = t & 127;
    const float4* w1e = (const float4*)(W1e + j * 16);
    const float4* w1u = (const float4*)(W1u + j * 16);
    float se = b1e[j], su = b1u[j];
    #pragma unroll
    for (int q = 0; q < 4; ++q) {
      float4 we = w1e[q], wu = w1u[q];
      float x0 = xs[bb][4 * q], x1 = xs[bb][4 * q + 1];
      float x2 = xs[bb][4 * q + 2], x3 = xs[bb][4 * q + 3];
      se += x0 * spf(we.x) + x1 * spf(we.y) + x2 * spf(we.z) + x3 * spf(we.w);
      su += x0 * spf(wu.x) + x1 * spf(wu.y) + x2 * spf(wu.z) + x3 * spf(wu.w);
    }
    he[bb][j] = spf(se);
    hu[bb][j] = spf(su);
  }
  __syncthreads();
  {  // emb head: 128 outputs x 2 threads (64 terms each)
    const int pair = t >> 1, half = t & 1;
    const int bb = pair >> 6, d = pair & 63;
    const float4* w2 = (const float4*)(W2e + d * 128 + half * 64);
    float s = 0.f;
    #pragma unroll
    for (int q = 0; q < 16; ++q) {
      float4 w = w2[q];
      const int j = half * 64 + 4 * q;
      s += he[bb][j]     * spf(w.x) + he[bb][j + 1] * spf(w.y)
         + he[bb][j + 2] * spf(w.z) + he[bb][j + 3] * spf(w.w);
    }
    s += __shfl_xor(s, 1);
    if (half == 0) out[bb * 64 + d] = gainp[0] * (s + b2e[d]);
  }
  if (t >= 192) {  // u head on wave 3
    const int tt = t - 192, bb = tt >> 5, l = tt & 31;
    float4 w = ((const float4*)W2u)[l];
    float s = hu[bb][4 * l]     * spf(w.x) + hu[bb][4 * l + 1] * spf(w.y)
            + hu[bb][4 * l + 2] * spf(w.z) + hu[bb][4 * l + 3] * spf(w.w);
    #pragma unroll
    for (int off = 1; off < 32; off <<= 1) s += __shfl_xor(s, off);
    if (l == 0) out[128 + bb] = s + b2u[0];
  }
}

extern "C" void kernel_launch(void* const* d_in, const int* in_sizes, int n_in,
                              void* d_out, int out_size, void* d_ws, size_t ws_size,
                              hipStream_t stream) {
  const float* raw  = (const float*)d_in[0];
  const float* W1e  = (const float*)d_in[1];
  const float* b1e  = (const float*)d_in[2];
  const float* W2e  = (const float*)d_in[3];
  const float* b2e  = (const float*)d_in[4];
  const float* W1u  = (const float*)d_in[5];
  const float* b1u  = (const float*)d_in[6];
  const float* W2u  = (const float*)d_in[7];
  const float* b2u  = (const float*)d_in[8];
  const float* gain = (const float*)d_in[9];
  float* out = (float*)d_out;

  float* ws     = (float*)d_ws;
  float* rowmed = ws;                   // 12288
  float* rowsa  = ws + NROW;            // 12288
  float* rowsq  = ws + 2 * NROW;        // 12288
  float* rowmx  = ws + 3 * NROW;        // 12288
  float* med    = ws + 4 * NROW;        // 8
  float* rowmad = ws + 4 * NROW + 8;    // 12288
  float* feats  = ws + 5 * NROW + 8;    // 32

  const int blocks = (B_ * H_) / 2;     // 3072 blocks, 4 waves each

  k_rowstats<<<blocks, 256, 0, stream>>>(raw, rowmed, rowsa, rowsq, rowmx);
  k_chanA<<<1, 512, 0, stream>>>(rowmed, rowsa, rowsq, rowmx, med, feats);
  k_madrows<<<blocks, 256, 0, stream>>>(raw, med, rowmad);
  k_tail<<<1, 256, 0, stream>>>(rowmad, feats,
                                W1e, b1e, W2e, b2e,
                                W1u, b1u, W2u, b2u, gain, out);
}